// Round 3
// baseline (230.133 us; speedup 1.0000x reference)
//
#include <hip/hip_runtime.h>
#include <utility>

// CGA Cl(4,1) sandwich pipeline: out = decode( V * encode(x) * ~V ), per point.
// HBM floor: 88 B/point * 2^21 = 184.5 MB -> ~27-29 us at achievable BW.
//
// R6. Post-mortem of R3/R4/R5: three structurally disjoint kernels
// (LDS-transpose bulk-sync / persistent pipelined / barrier-free AoS stream)
// landed at 209.8 / 216.7 / 212.0 us. The shared term dominates: HBM traffic
// (floor 27-29 us) plus ~175 us of harness-fixed fills (2 x 78.5 us poison
// fills) and dozens of small reset dispatches + inter-dispatch gaps. Best
// estimate: the kernel itself is already ~30-38 us, near the BW roofline.
// This round removes R5's two residual (falsifiable) inefficiencies:
//   1. R5 spread each thread's 4 points 2^19 apart -> each versor line
//      touched 4x across a wide temporal window while 12-16 waves thrash the
//      32 KB L1 -> L2 re-fetch. R6 gives each thread 2 CONSECUTIVE points:
//      128 B contiguous versor per lane (8 x float4, same-line touches
//      back-to-back -> guaranteed L1 hits), 24 B x, 24 B out.
//   2. R5's x loads / out stores were scalar dwords. R6: everything is a
//      vectorized 16 B or 8 B access (float2 is 8-B aligned at 24-B/lane
//      pitch). No LDS, no barriers, ~80 VGPR.
//   3. nontemporal hints on all global accesses: every stream is touch-once,
//      so keep it from churning L2/LLC.
// If this lands >= 210 us (no gain from a strictly better pattern), the
// roofline-convergence conclusion is confirmed.

namespace cga {

__host__ __device__ constexpr int popc5(int x) {
    int c = 0;
    for (int i = 0; i < 5; ++i) c += (x >> i) & 1;
    return c;
}
__host__ __device__ constexpr int blade_of_even(int idx) {
    int cnt = 0;
    for (int b = 0; b < 32; ++b)
        if ((popc5(b) & 1) == 0) { if (cnt == idx) return b; ++cnt; }
    return 0;
}
__host__ __device__ constexpr int blade_of_odd(int idx) {
    int cnt = 0;
    for (int b = 0; b < 32; ++b)
        if ((popc5(b) & 1) == 1) { if (cnt == idx) return b; ++cnt; }
    return 0;
}
__host__ __device__ constexpr int even_index(int blade) {
    int idx = 0;
    for (int b = 0; b < blade; ++b) if ((popc5(b) & 1) == 0) ++idx;
    return idx;
}
__host__ __device__ constexpr int odd_index(int blade) {
    int idx = 0;
    for (int b = 0; b < blade; ++b) if ((popc5(b) & 1) == 1) ++idx;
    return idx;
}
__host__ __device__ constexpr int mul_sign(int a, int b) {
    int s = 0;
    for (int t = a >> 1; t; t >>= 1) s += popc5(t & b);
    int sign = (s & 1) ? -1 : 1;
    if ((a & b) & 16) sign = -sign;   // shared e5 squares to -1
    return sign;
}
__host__ __device__ constexpr int rev_sign(int b) {
    int g = popc5(b);
    return ((g * (g - 1) / 2) & 1) ? -1 : 1;
}

struct Tables {
    int t1_dst[16][5];
    int t1_sgn[16][5];
    int t2_e[16][5];
    int t2_sgn[16][5];
};

__host__ __device__ constexpr Tables make_tables() {
    Tables r{};
    for (int ie = 0; ie < 16; ++ie) {
        const int a = blade_of_even(ie);
        for (int ip = 0; ip < 5; ++ip) {
            const int b = 1 << ip;
            const int c = a ^ b;
            r.t1_dst[ie][ip] = odd_index(c);
            r.t1_sgn[ie][ip] = mul_sign(a, b);
        }
    }
    for (int io = 0; io < 16; ++io) {
        const int a = blade_of_odd(io);
        for (int iq = 0; iq < 5; ++iq) {
            const int c = 1 << iq;
            const int b = a ^ c;   // connecting blade: always even grade
            r.t2_e[io][iq]   = even_index(b);
            r.t2_sgn[io][iq] = mul_sign(a, b) * rev_sign(b);
        }
    }
    return r;
}

constexpr Tables TAB = make_tables();

}  // namespace cga

template <int IE, int IP>
__device__ __forceinline__ void t1_term(const float (&v)[16], const float (&p)[5],
                                        float (&mx)[16]) {
    constexpr int dst = cga::TAB.t1_dst[IE][IP];
    constexpr int sgn = cga::TAB.t1_sgn[IE][IP];
    if constexpr (sgn >= 0) mx[dst] = __builtin_fmaf( v[IE], p[IP], mx[dst]);
    else                    mx[dst] = __builtin_fmaf(-v[IE], p[IP], mx[dst]);
}
template <std::size_t... I>
__device__ __forceinline__ void t1_all(const float (&v)[16], const float (&p)[5],
                                       float (&mx)[16], std::index_sequence<I...>) {
    (t1_term<(int)(I / 5), (int)(I % 5)>(v, p, mx), ...);
}
template <int IO, int IQ>
__device__ __forceinline__ void t2_term(const float (&v)[16], const float (&mx)[16],
                                        float (&q)[5]) {
    constexpr int e   = cga::TAB.t2_e[IO][IQ];
    constexpr int sgn = cga::TAB.t2_sgn[IO][IQ];
    if constexpr (sgn >= 0) q[IQ] = __builtin_fmaf( mx[IO], v[e], q[IQ]);
    else                    q[IQ] = __builtin_fmaf(-mx[IO], v[e], q[IQ]);
}
template <std::size_t... I>
__device__ __forceinline__ void t2_all(const float (&v)[16], const float (&mx)[16],
                                       float (&q)[5], std::index_sequence<I...>) {
    (t2_term<(int)(I / 5), (int)(I % 5)>(v, mx, q), ...);
}

__device__ __forceinline__ void cga_compute(const float (&v)[16],
                                            float x0, float x1, float x2,
                                            float& o0, float& o1, float& o2) {
    const float hs = 0.5f * (x0 * x0 + x1 * x1 + x2 * x2);
    const float p[5] = {x0, x1, x2, hs - 0.5f, hs + 0.5f};
    float mx[16] = {};
    t1_all(v, p, mx, std::make_index_sequence<16 * 5>{});
    float q[5] = {};
    t2_all(v, mx, q, std::make_index_sequence<16 * 5>{});
    const float inv = 1.0f / (q[4] - q[3]);
    o0 = q[0] * inv;
    o1 = q[1] * inv;
    o2 = q[2] * inv;
}

using f32x4 = __attribute__((ext_vector_type(4))) float;
using f32x2 = __attribute__((ext_vector_type(2))) float;

// ---- consecutive-pair AoS streaming kernel: 2 points/thread, no LDS ----
// Requires n % 512 == 0 (true here: n = 2^21).
__global__ __launch_bounds__(256) void cga_pair_kernel(
    const float* __restrict__ versor,
    const float* __restrict__ x,
    float* __restrict__ out)
{
    const size_t g = (size_t)blockIdx.x * 256 + threadIdx.x;  // pair index

    const f32x4* vg = reinterpret_cast<const f32x4*>(versor);
    const f32x2* xg = reinterpret_cast<const f32x2*>(x);
    f32x2* og = reinterpret_cast<f32x2*>(out);

    // ---- loads: 128 B contiguous versor + 24 B contiguous x per lane ----
    // All 11 loads issued before any compute; nontemporal (touch-once).
    f32x4 f[8];
#pragma unroll
    for (int j = 0; j < 8; ++j)
        f[j] = __builtin_nontemporal_load(vg + g * 8 + j);
    f32x2 xp[3];
#pragma unroll
    for (int m = 0; m < 3; ++m)
        xp[m] = __builtin_nontemporal_load(xg + g * 3 + m);

    // ---- point 0: versor floats [0..16) = f[0..3], x = (xp0.x, xp0.y, xp1.x) ----
    const float v0[16] = {f[0].x, f[0].y, f[0].z, f[0].w,
                          f[1].x, f[1].y, f[1].z, f[1].w,
                          f[2].x, f[2].y, f[2].z, f[2].w,
                          f[3].x, f[3].y, f[3].z, f[3].w};
    float a0, a1, a2;
    cga_compute(v0, xp[0].x, xp[0].y, xp[1].x, a0, a1, a2);

    // ---- point 1: versor floats [16..32) = f[4..7], x = (xp1.y, xp2.x, xp2.y) ----
    const float v1[16] = {f[4].x, f[4].y, f[4].z, f[4].w,
                          f[5].x, f[5].y, f[5].z, f[5].w,
                          f[6].x, f[6].y, f[6].z, f[6].w,
                          f[7].x, f[7].y, f[7].z, f[7].w};
    float b0, b1, b2;
    cga_compute(v1, xp[1].y, xp[2].x, xp[2].y, b0, b1, b2);

    // ---- stores: 24 B contiguous per lane, 3 x float2, nontemporal ----
    f32x2 s0; s0.x = a0; s0.y = a1;
    f32x2 s1; s1.x = a2; s1.y = b0;
    f32x2 s2; s2.x = b1; s2.y = b2;
    __builtin_nontemporal_store(s0, og + g * 3 + 0);
    __builtin_nontemporal_store(s1, og + g * 3 + 1);
    __builtin_nontemporal_store(s2, og + g * 3 + 2);
}

// ---- fallback for n not divisible by 512 (not hit for this problem) ----
__global__ __launch_bounds__(256) void cga_simple_kernel(
    const float* __restrict__ versor,
    const float* __restrict__ x,
    float* __restrict__ out,
    int n)
{
    const int i = blockIdx.x * blockDim.x + threadIdx.x;
    if (i >= n) return;
    const float4* v4 = reinterpret_cast<const float4*>(versor) + (size_t)i * 4;
    const float4 a0 = v4[0], a1 = v4[1], a2 = v4[2], a3 = v4[3];
    const float v[16] = {a0.x, a0.y, a0.z, a0.w, a1.x, a1.y, a1.z, a1.w,
                         a2.x, a2.y, a2.z, a2.w, a3.x, a3.y, a3.z, a3.w};
    float o0, o1, o2;
    cga_compute(v, x[(size_t)3 * i], x[(size_t)3 * i + 1], x[(size_t)3 * i + 2],
                o0, o1, o2);
    out[(size_t)3 * i + 0] = o0;
    out[(size_t)3 * i + 1] = o1;
    out[(size_t)3 * i + 2] = o2;
}

extern "C" void kernel_launch(void* const* d_in, const int* in_sizes, int n_in,
                              void* d_out, int out_size, void* d_ws, size_t ws_size,
                              hipStream_t stream) {
    const float* versor = (const float*)d_in[0];  // (N, 16) fp32
    const float* x      = (const float*)d_in[1];  // (N, 3)  fp32
    float* out          = (float*)d_out;          // (N, 3)  fp32
    const int n = in_sizes[0] / 16;

    if ((n & 511) == 0) {
        const int pairs = n / 2;                  // 2^20
        cga_pair_kernel<<<pairs / 256, 256, 0, stream>>>(versor, x, out);
    } else {
        cga_simple_kernel<<<(n + 255) / 256, 256, 0, stream>>>(versor, x, out, n);
    }
}

// Round 4
// 209.580 us; speedup vs baseline: 1.0981x; 1.0981x over previous
//
#include <hip/hip_runtime.h>
#include <utility>

// CGA Cl(4,1) sandwich pipeline: out = decode( V * encode(x) * ~V ), per point.
// HBM floor: 88 B/point * 2^21 = 184.5 MB -> ~27-29 us at achievable BW.
//
// R7: exact restore of the session-best R3 kernel (209.8 us).
// Post-mortem trail: R4 persistent-pipelined 216.7 (occupancy/lockstep loss),
// R5 spread-AoS 212.0, R6 pair-AoS+nontemporal 230.1 (nt hints broke the
// cache-merging both AoS layouts depend on -- a bundled-variable error).
// Three clean structures (LDS-transpose / spread-AoS / tiled) land within
// 2.2 us: the shared term (184.5 MB HBM traffic + ~157 us harness poison
// fills + small reset dispatches) dominates. This round restores the proven
// best AND gives the session's first repeat-measurement of identical source,
// establishing the run-to-run noise bar. Pre-commit: <=212 -> convergence
// confirmed, declare roofline; >214 -> deltas were noise, re-evaluate.
//
// Structure (R3): 256 points per 256-thread block, all global I/O dense
// 16 B/lane float4; versor transposed through XOR-swizzled component-major
// LDS (writes 2-way aliased = free per m136; reads conflict-free); x and out
// staged through LDS so their global accesses are dense float4 too.

namespace cga {

__host__ __device__ constexpr int popc5(int x) {
    int c = 0;
    for (int i = 0; i < 5; ++i) c += (x >> i) & 1;
    return c;
}
__host__ __device__ constexpr int blade_of_even(int idx) {
    int cnt = 0;
    for (int b = 0; b < 32; ++b)
        if ((popc5(b) & 1) == 0) { if (cnt == idx) return b; ++cnt; }
    return 0;
}
__host__ __device__ constexpr int blade_of_odd(int idx) {
    int cnt = 0;
    for (int b = 0; b < 32; ++b)
        if ((popc5(b) & 1) == 1) { if (cnt == idx) return b; ++cnt; }
    return 0;
}
__host__ __device__ constexpr int even_index(int blade) {
    int idx = 0;
    for (int b = 0; b < blade; ++b) if ((popc5(b) & 1) == 0) ++idx;
    return idx;
}
__host__ __device__ constexpr int odd_index(int blade) {
    int idx = 0;
    for (int b = 0; b < blade; ++b) if ((popc5(b) & 1) == 1) ++idx;
    return idx;
}
__host__ __device__ constexpr int mul_sign(int a, int b) {
    int s = 0;
    for (int t = a >> 1; t; t >>= 1) s += popc5(t & b);
    int sign = (s & 1) ? -1 : 1;
    if ((a & b) & 16) sign = -sign;   // shared e5 squares to -1
    return sign;
}
__host__ __device__ constexpr int rev_sign(int b) {
    int g = popc5(b);
    return ((g * (g - 1) / 2) & 1) ? -1 : 1;
}

struct Tables {
    int t1_dst[16][5];
    int t1_sgn[16][5];
    int t2_e[16][5];
    int t2_sgn[16][5];
};

__host__ __device__ constexpr Tables make_tables() {
    Tables r{};
    for (int ie = 0; ie < 16; ++ie) {
        const int a = blade_of_even(ie);
        for (int ip = 0; ip < 5; ++ip) {
            const int b = 1 << ip;
            const int c = a ^ b;
            r.t1_dst[ie][ip] = odd_index(c);
            r.t1_sgn[ie][ip] = mul_sign(a, b);
        }
    }
    for (int io = 0; io < 16; ++io) {
        const int a = blade_of_odd(io);
        for (int iq = 0; iq < 5; ++iq) {
            const int c = 1 << iq;
            const int b = a ^ c;   // connecting blade: always even grade
            r.t2_e[io][iq]   = even_index(b);
            r.t2_sgn[io][iq] = mul_sign(a, b) * rev_sign(b);
        }
    }
    return r;
}

constexpr Tables TAB = make_tables();

}  // namespace cga

template <int IE, int IP>
__device__ __forceinline__ void t1_term(const float (&v)[16], const float (&p)[5],
                                        float (&mx)[16]) {
    constexpr int dst = cga::TAB.t1_dst[IE][IP];
    constexpr int sgn = cga::TAB.t1_sgn[IE][IP];
    if constexpr (sgn >= 0) mx[dst] = __builtin_fmaf( v[IE], p[IP], mx[dst]);
    else                    mx[dst] = __builtin_fmaf(-v[IE], p[IP], mx[dst]);
}
template <std::size_t... I>
__device__ __forceinline__ void t1_all(const float (&v)[16], const float (&p)[5],
                                       float (&mx)[16], std::index_sequence<I...>) {
    (t1_term<(int)(I / 5), (int)(I % 5)>(v, p, mx), ...);
}
template <int IO, int IQ>
__device__ __forceinline__ void t2_term(const float (&v)[16], const float (&mx)[16],
                                        float (&q)[5]) {
    constexpr int e   = cga::TAB.t2_e[IO][IQ];
    constexpr int sgn = cga::TAB.t2_sgn[IO][IQ];
    if constexpr (sgn >= 0) q[IQ] = __builtin_fmaf( mx[IO], v[e], q[IQ]);
    else                    q[IQ] = __builtin_fmaf(-mx[IO], v[e], q[IQ]);
}
template <std::size_t... I>
__device__ __forceinline__ void t2_all(const float (&v)[16], const float (&mx)[16],
                                       float (&q)[5], std::index_sequence<I...>) {
    (t2_term<(int)(I / 5), (int)(I % 5)>(v, mx, q), ...);
}

__device__ __forceinline__ void cga_compute(const float (&v)[16],
                                            float x0, float x1, float x2,
                                            float& o0, float& o1, float& o2) {
    const float hs = 0.5f * (x0 * x0 + x1 * x1 + x2 * x2);
    const float p[5] = {x0, x1, x2, hs - 0.5f, hs + 0.5f};
    float mx[16] = {};
    t1_all(v, p, mx, std::make_index_sequence<16 * 5>{});
    float q[5] = {};
    t2_all(v, mx, q, std::make_index_sequence<16 * 5>{});
    const float inv = 1.0f / (q[4] - q[3]);
    o0 = q[0] * inv;
    o1 = q[1] * inv;
    o2 = q[2] * inv;
}

// ---- tiled kernel: 256 points per 256-thread block, all-dense global I/O ----
// Requires n % 256 == 0 (true for this problem: n = 2^21).
__global__ __launch_bounds__(256) void cga_tiled_kernel(
    const float* __restrict__ versor,
    const float* __restrict__ x,
    float* __restrict__ out)
{
    __shared__ float lds_v[16 * 256];  // component-major, XOR-swizzled
    __shared__ float lds_x[3 * 256];
    __shared__ float lds_o[3 * 256];

    const int t   = threadIdx.x;
    const int blk = blockIdx.x;

    // ---- dense cooperative loads (16 B/lane contiguous) ----
    const float4* vg = reinterpret_cast<const float4*>(versor);
    float4 f[4];
#pragma unroll
    for (int j = 0; j < 4; ++j)
        f[j] = vg[(size_t)blk * 1024 + (size_t)(j * 256 + t)];

    float4 xf = make_float4(0.f, 0.f, 0.f, 0.f);
    if (t < 192)
        xf = reinterpret_cast<const float4*>(x)[(size_t)blk * 192 + t];

    // ---- scatter versor float4s to component-major LDS ----
    // global float4 (j*256+t) = flat floats [1024j+4t, +4) = point p = 64j+t/4,
    // comps c = 4*(t&3)+w. LDS word for (c,p): c*256 + (p ^ (4*(c&7))).
    {
        const int b = t & 3;
        const int a = t >> 2;
#pragma unroll
        for (int j = 0; j < 4; ++j) {
            const int p = 64 * j + a;
            const float w4[4] = {f[j].x, f[j].y, f[j].z, f[j].w};
#pragma unroll
            for (int w = 0; w < 4; ++w) {
                const int c = 4 * b + w;
                lds_v[c * 256 + (p ^ (4 * (c & 7)))] = w4[w];
            }
        }
    }
    if (t < 192)
        reinterpret_cast<float4*>(lds_x)[t] = xf;

    __syncthreads();

    // ---- per-thread gather (conflict-free) + compute ----
    float v[16];
#pragma unroll
    for (int c = 0; c < 16; ++c)
        v[c] = lds_v[c * 256 + (t ^ (4 * (c & 7)))];

    const float x0 = lds_x[3 * t + 0];
    const float x1 = lds_x[3 * t + 1];
    const float x2 = lds_x[3 * t + 2];

    float o0, o1, o2;
    cga_compute(v, x0, x1, x2, o0, o1, o2);

    lds_o[3 * t + 0] = o0;
    lds_o[3 * t + 1] = o1;
    lds_o[3 * t + 2] = o2;

    __syncthreads();

    // ---- dense cooperative store ----
    if (t < 192) {
        const float4 ov = reinterpret_cast<const float4*>(lds_o)[t];
        reinterpret_cast<float4*>(out)[(size_t)blk * 192 + t] = ov;
    }
}

// ---- fallback for n not divisible by 256 (not hit for this problem) ----
__global__ __launch_bounds__(256) void cga_simple_kernel(
    const float* __restrict__ versor,
    const float* __restrict__ x,
    float* __restrict__ out,
    int n)
{
    const int i = blockIdx.x * blockDim.x + threadIdx.x;
    if (i >= n) return;
    const float4* v4 = reinterpret_cast<const float4*>(versor) + (size_t)i * 4;
    const float4 a0 = v4[0], a1 = v4[1], a2 = v4[2], a3 = v4[3];
    const float v[16] = {a0.x, a0.y, a0.z, a0.w, a1.x, a1.y, a1.z, a1.w,
                         a2.x, a2.y, a2.z, a2.w, a3.x, a3.y, a3.z, a3.w};
    float o0, o1, o2;
    cga_compute(v, x[(size_t)3 * i], x[(size_t)3 * i + 1], x[(size_t)3 * i + 2],
                o0, o1, o2);
    out[(size_t)3 * i + 0] = o0;
    out[(size_t)3 * i + 1] = o1;
    out[(size_t)3 * i + 2] = o2;
}

extern "C" void kernel_launch(void* const* d_in, const int* in_sizes, int n_in,
                              void* d_out, int out_size, void* d_ws, size_t ws_size,
                              hipStream_t stream) {
    const float* versor = (const float*)d_in[0];  // (N, 16) fp32
    const float* x      = (const float*)d_in[1];  // (N, 3)  fp32
    float* out          = (float*)d_out;          // (N, 3)  fp32
    const int n = in_sizes[0] / 16;

    if ((n & 255) == 0) {
        cga_tiled_kernel<<<n / 256, 256, 0, stream>>>(versor, x, out);
    } else {
        cga_simple_kernel<<<(n + 255) / 256, 256, 0, stream>>>(versor, x, out, n);
    }
}